// Round 6
// baseline (26269.724 us; speedup 1.0000x reference)
//
#include <hip/hip_runtime.h>
#include <cstdint>

// CharRNN fused kernel, round 10 — MI355X (gfx950).
//
// STRUCTURAL RESET. r4-r9 used 8 clusters x 16 WGs exchanging h through
// global memory every step. Measured across r5/r7/r8/r9: every agent-scope
// leg (store-ack, flag prop, poll, sweep) is ~900cy, they serialize to
// ~7k cy/step, XCD-local shortcuts are unsound (sc1/plain stores invisible
// to sc0 loads through stale L1/L2 lines), and speculation loses in
// lockstep (r9: +33% FETCH, +440us).
//
// Round-10: the cluster existed only because W_hh hi+lo (1 MB) was assumed
// too big for one WG. It fits: 1024-thread WG = 16 waves x 256 VGPRs for
// weights (cap 512/wave at 4 waves/SIMD). So: 8 WGs, each owning 16 batch
// rows and the ENTIRE recurrence — ZERO cross-WG communication.
//  - wave w: hidden cols [32w,32w+32) (W_hh hi+lo, W_ih hi+lo in regs);
//    waves 0-7 also own vocab tile w (W_fc hi-only in regs).
//  - h state: LDS, double-buffered MFMA A-fragments, hi+lo bf16, EXACT
//    r5-verified layout idx16(b,jg) = (jg>>5)*512+((jg&31)>>3)*128+b*8+
//    (jg&7), pair-packed b32 via shfl_xor(1) (r5's proven trick).
//  - x-term: ep table (256 KB f32, no LDS fit) replaced by 3 MFMAs/tile
//    from LDS emb (8 KB f32) x register W_ih hi/lo (err ~2^-18). Biases
//    fold into acc init (f32, exact).
//  - logits lag 1 step (wave reads A(h(t)) = hs[t-1]); epilogue t=TT.
//  - per step: ~472 MFMA/SIMD (~2290cy) + 32 b128 ds_reads/wave
//    (overlapped) + tanh/pack + ONE __syncthreads. ~2.7-3k cy/step
//    vs r5's 7k. No protocol, no hang surface, no workspace.

typedef short bf16x8 __attribute__((ext_vector_type(8)));
typedef float f32x4 __attribute__((ext_vector_type(4)));

#define VOCAB 128
#define EMB   16
#define HID   512
#define TT    1024
#define BROWS 16     // batch rows per WG
#define NWG   8

#define MFMA __builtin_amdgcn_mfma_f32_16x16x32_bf16

__device__ __forceinline__ unsigned short f2bf(float f) {
  uint32_t u = __builtin_bit_cast(uint32_t, f);
  u += 0x7FFFu + ((u >> 16) & 1u);
  return (unsigned short)(u >> 16);
}
__device__ __forceinline__ float bf2f(unsigned short s) {
  uint32_t u = (uint32_t)s << 16;
  return __builtin_bit_cast(float, u);
}
__device__ __forceinline__ float ftanh(float z) {
  z = fminf(15.f, fmaxf(-15.f, z));
  float e = __expf(2.f * z);
  return (e - 1.f) * __builtin_amdgcn_rcpf(e + 1.f);
}

__global__ __launch_bounds__(1024, 1) void charrnn_kernel(
    const int* __restrict__ xin,
    const float* __restrict__ emb,
    const float* __restrict__ wih,
    const float* __restrict__ whh,
    const float* __restrict__ bih,
    const float* __restrict__ bhh,
    const float* __restrict__ wfc,
    const float* __restrict__ bfc,
    float* __restrict__ out)
{
  // h as A-frags (hi+lo bf16), double-buffered: 2 x 16 KB each
  __shared__ __align__(16) unsigned short a_hi[2][16 * 512];  // 32 KB
  __shared__ __align__(16) unsigned short a_lo[2][16 * 512];  // 32 KB
  __shared__ float emb_s[VOCAB * EMB];                        // 8 KB
  __shared__ float bsum_s[HID];                               // 2 KB
  __shared__ float bfc_s[VOCAB];                              // 0.5 KB
  __shared__ unsigned char xtok[BROWS * TT];                  // 16 KB
  // total ~90.5 KB

  const int tid  = threadIdx.x;
  const int w    = tid >> 6;        // wave 0..15
  const int lane = tid & 63;
  const int col  = lane & 15;
  const int quad = lane >> 4;
  const int rb   = blockIdx.x * BROWS;

  // ---- weights -> registers (one-time; all indices compile-time) ----
  bf16x8 whh_h0[16], whh_l0[16], whh_h1[16], whh_l1[16];
  bf16x8 wih_h0, wih_l0, wih_h1, wih_l1;
  bf16x8 wfc_f[16];
  {
    const int nrow0 = w * 32 + col;         // tc = 0
    const int nrow1 = nrow0 + 16;           // tc = 1
    const float* wr0 = whh + (size_t)nrow0 * HID + quad * 8;
    const float* wr1 = whh + (size_t)nrow1 * HID + quad * 8;
    #pragma unroll
    for (int ks = 0; ks < 16; ++ks) {
      bf16x8 h0, l0, h1, l1;
      #pragma unroll
      for (int j = 0; j < 8; ++j) {
        float v0 = wr0[ks * 32 + j];
        unsigned short a = f2bf(v0);
        h0[j] = (short)a; l0[j] = (short)f2bf(v0 - bf2f(a));
        float v1 = wr1[ks * 32 + j];
        unsigned short b = f2bf(v1);
        h1[j] = (short)b; l1[j] = (short)f2bf(v1 - bf2f(b));
      }
      whh_h0[ks] = h0; whh_l0[ks] = l0;
      whh_h1[ks] = h1; whh_l1[ks] = l1;
    }
    // W_ih: K=16 occupies k-slots 0..15 (quads 0,1); zeros elsewhere
    bf16x8 z = {0,0,0,0,0,0,0,0};
    wih_h0 = z; wih_l0 = z; wih_h1 = z; wih_l1 = z;
    if (quad < 2) {
      const float* p0 = wih + (size_t)nrow0 * EMB + quad * 8;
      const float* p1 = wih + (size_t)nrow1 * EMB + quad * 8;
      #pragma unroll
      for (int j = 0; j < 8; ++j) {
        float v0 = p0[j];
        unsigned short a = f2bf(v0);
        wih_h0[j] = (short)a; wih_l0[j] = (short)f2bf(v0 - bf2f(a));
        float v1 = p1[j];
        unsigned short b = f2bf(v1);
        wih_h1[j] = (short)b; wih_l1[j] = (short)f2bf(v1 - bf2f(b));
      }
    }
    if (w < 8) {
      const float* wr = wfc + (size_t)(w * 16 + col) * HID + quad * 8;
      #pragma unroll
      for (int ks = 0; ks < 16; ++ks) {
        bf16x8 f;
        #pragma unroll
        for (int j = 0; j < 8; ++j) f[j] = (short)f2bf(wr[ks * 32 + j]);
        wfc_f[ks] = f;
      }
    }
  }

  // ---- LDS init ----
  for (int i = tid; i < 16 * 512; i += 1024) { a_hi[0][i] = 0; a_lo[0][i] = 0; }
  for (int i = tid; i < VOCAB * EMB; i += 1024) emb_s[i] = emb[i];
  if (tid < HID)   bsum_s[tid] = bih[tid] + bhh[tid];
  if (tid < VOCAB) bfc_s[tid] = bfc[tid];
  for (int i = tid; i < BROWS * TT; i += 1024) {
    int b = i >> 10, t = i & 1023;
    xtok[i] = (unsigned char)xin[(rb + b) * TT + t];
  }
  __syncthreads();

  const float bsv0 = bsum_s[w * 32 + col];
  const float bsv1 = bsum_s[w * 32 + 16 + col];
  const float bfcv = (w < 8) ? bfc_s[w * 16 + col] : 0.f;

  // ---- main time loop: ONE barrier per step, no global protocol ----
  #pragma unroll 1
  for (int t = 0; t <= TT; ++t) {
    const int par = t & 1;
    const unsigned short* Ah = a_hi[par];
    const unsigned short* Al = a_lo[par];
    const bool dorec = (t < TT);
    const bool dolog = (w < 8) && (t >= 1);

    // x-frag: A-operand = emb rows of this step's 16 tokens (K=16 padded)
    bf16x8 xah = {0,0,0,0,0,0,0,0}, xal = {0,0,0,0,0,0,0,0};
    if (dorec && quad < 2) {
      const int tok = (int)xtok[col * TT + t];
      const float* ev = emb_s + tok * EMB + quad * 8;
      #pragma unroll
      for (int j = 0; j < 8; ++j) {
        float v = ev[j];
        unsigned short a = f2bf(v);
        xah[j] = (short)a; xal[j] = (short)f2bf(v - bf2f(a));
      }
    }

    f32x4 racc0 = {bsv0, bsv0, bsv0, bsv0};
    f32x4 racc1 = {bsv1, bsv1, bsv1, bsv1};
    f32x4 lacc  = {bfcv, bfcv, bfcv, bfcv};
    if (dorec) {
      racc0 = MFMA(xah, wih_h0, racc0, 0, 0, 0);
      racc0 = MFMA(xal, wih_h0, racc0, 0, 0, 0);
      racc0 = MFMA(xah, wih_l0, racc0, 0, 0, 0);
      racc1 = MFMA(xah, wih_h1, racc1, 0, 0, 0);
      racc1 = MFMA(xal, wih_h1, racc1, 0, 0, 0);
      racc1 = MFMA(xah, wih_l1, racc1, 0, 0, 0);
    }

    #pragma unroll
    for (int ks = 0; ks < 16; ++ks) {
      bf16x8 ah = *(const bf16x8*)&Ah[ks * 512 + lane * 8];
      bf16x8 al = *(const bf16x8*)&Al[ks * 512 + lane * 8];
      if (dorec) {
        racc0 = MFMA(ah, whh_h0[ks], racc0, 0, 0, 0);
        racc0 = MFMA(al, whh_h0[ks], racc0, 0, 0, 0);
        racc0 = MFMA(ah, whh_l0[ks], racc0, 0, 0, 0);
        racc1 = MFMA(ah, whh_h1[ks], racc1, 0, 0, 0);
        racc1 = MFMA(al, whh_h1[ks], racc1, 0, 0, 0);
        racc1 = MFMA(ah, whh_l1[ks], racc1, 0, 0, 0);
      }
      if (dolog) {
        lacc = MFMA(ah, wfc_f[ks], lacc, 0, 0, 0);
        lacc = MFMA(al, wfc_f[ks], lacc, 0, 0, 0);
      }
    }

    // logits for time t-1 (C-layout: col=lane&15 -> vocab, rows via quad)
    if (dolog) {
      #pragma unroll
      for (int i = 0; i < 4; ++i) {
        out[((size_t)(rb + quad * 4 + i) * TT + (t - 1)) * VOCAB
            + w * 16 + col] = lacc[i];
      }
    }

    // tanh + hi/lo split + pair-pack (r5's verified shfl_xor trick) ->
    // next A-frag buffer. jg = w*32 + tc*16 + col; b = quad*4 + i.
    if (dorec) {
      uint32_t* dH = (uint32_t*)a_hi[par ^ 1];
      uint32_t* dL = (uint32_t*)a_lo[par ^ 1];
      const int colE = col & ~1;
      const int base0 = w * 256 + ((colE) >> 3) * 64 + ((colE & 7) >> 1);
      const int base1 = w * 256 + ((16 + colE) >> 3) * 64 + ((colE & 7) >> 1);
      #pragma unroll
      for (int i = 0; i < 4; ++i) {
        const int b4 = (quad * 4 + i) * 4;
        {
          float h = ftanh(racc0[i]);
          unsigned short hi = f2bf(h);
          unsigned short lo = f2bf(h - bf2f(hi));
          uint32_t pk = (uint32_t)hi | ((uint32_t)lo << 16);
          uint32_t pp = (uint32_t)__shfl_xor((int)pk, 1);
          if (col & 1) dL[base0 + b4] = (pp >> 16) | (pk & 0xFFFF0000u);
          else         dH[base0 + b4] = (pk & 0xFFFFu) | (pp << 16);
        }
        {
          float h = ftanh(racc1[i]);
          unsigned short hi = f2bf(h);
          unsigned short lo = f2bf(h - bf2f(hi));
          uint32_t pk = (uint32_t)hi | ((uint32_t)lo << 16);
          uint32_t pp = (uint32_t)__shfl_xor((int)pk, 1);
          if (col & 1) dL[base1 + b4] = (pp >> 16) | (pk & 0xFFFF0000u);
          else         dH[base1 + b4] = (pk & 0xFFFFu) | (pp << 16);
        }
      }
    }
    __syncthreads();  // writes to buf[par^1] ready; reads of buf[par] done
  }
}

extern "C" void kernel_launch(void* const* d_in, const int* in_sizes, int n_in,
                              void* d_out, int out_size, void* d_ws, size_t ws_size,
                              hipStream_t stream) {
  (void)in_sizes; (void)n_in; (void)out_size; (void)d_ws; (void)ws_size;

  const int*   x    = (const int*)d_in[0];
  const float* embp = (const float*)d_in[1];
  const float* W_ih = (const float*)d_in[2];
  const float* W_hh = (const float*)d_in[3];
  const float* b_ih = (const float*)d_in[4];
  const float* b_hh = (const float*)d_in[5];
  const float* W_fc = (const float*)d_in[6];
  const float* b_fc = (const float*)d_in[7];

  charrnn_kernel<<<NWG, 1024, 0, stream>>>(x, embp, W_ih, W_hh, b_ih, b_hh,
                                           W_fc, b_fc, (float*)d_out);
}

// Round 7
// 15248.924 us; speedup vs baseline: 1.7227x; 1.7227x over previous
//
#include <hip/hip_runtime.h>
#include <cstdint>

// CharRNN fused kernel, round 11 — MI355X (gfx950).
//
// Measured constraints driving this design:
//  - r5 (3018us): agent-scope exchange legs are ~900cy each and serialize
//    to ~7k cy/step when one cluster-step depends on the previous.
//  - r7/r8: XCD-local (sc0/plain) shortcuts are UNSOUND (stale L1/L2 lines).
//  - r9 (3459us): tag-validated transport WORKS (absmax 0.0078125) but
//    zero-margin speculation always misses in lockstep.
//  - r10 (26ms): per-CU register file = 2048 wave-VGPRs TOTAL (512KB).
//    16-wave blocks cap at 128 VGPR/wave; W_hh hi+lo (4096 wave-VGPRs)
//    can NEVER be single-CU-resident. Col-split cluster is forced.
//
// Round-11: LATENCY-HIDING cluster. Batch rows are independent recurrence
// streams; 2 clusters x 16 members, each cluster time-multiplexes 4 batch
// groups (16 rows each) in a slot schedule: slot s -> (g = s&3, t = s>>2).
// While group g's h(t) propagates (~2 slots = ~1900cy), the cluster
// computes g+1..g+3. The sweep becomes a PREFETCH: issued at slot s for
// slot s+2 (data published at slot s-2 -> ample margin), tag-validated
// (r9's exact verified format: word = q21<<11 | gen-tag11, frag-linear
// layout) at consume time = pure VALU. No flags, no acks, no polls —
// tag-retry IS the synchronizer; rare retries self-correct drift.
// Overwrite safety (r5 induction, distance 2): member publishes gen t+2
// only after validating gen t+1, which requires every member published
// t+1, which requires they validated t. Cross-launch residue killed by
// zeroing the 512KB data region (tag 0 matches no live gen 1..1024).
//
// Slot cost: validate+unpack ~300cy + 48 MFMA (rec) / 32 MFMA (logits)
// + tanh/pack + 2 barriers ~= 900cy -> 4101 slots ~= 1.5ms predicted.

typedef short bf16x8 __attribute__((ext_vector_type(8)));
typedef float f32x4 __attribute__((ext_vector_type(4)));

#define VOCAB 128
#define EMB   16
#define HID   512
#define TT    1024
#define GPC   4      // batch groups per cluster (16 rows each)
#define NCLUST 2
#define MEMB  16
#define NWG   (NCLUST * MEMB)
#define CLW   8192   // dwords per (cluster,group,parity) region (32 KB)
#define PJC   33
#define NVALID (GPC * (TT + 1))
#define NSLOT  (NVALID + 1)

#define MFMA16 __builtin_amdgcn_mfma_f32_16x16x32_bf16

__device__ __forceinline__ unsigned short f2bf(float f) {
  uint32_t u = __builtin_bit_cast(uint32_t, f);
  u += 0x7FFFu + ((u >> 16) & 1u);
  return (unsigned short)(u >> 16);
}
__device__ __forceinline__ float bf2f(unsigned short s) {
  uint32_t u = (uint32_t)s << 16;
  return __builtin_bit_cast(float, u);
}
__device__ __forceinline__ float ftanh(float z) {
  z = fminf(15.f, fmaxf(-15.f, z));
  float e = __expf(2.f * z);
  return (e - 1.f) * __builtin_amdgcn_rcpf(e + 1.f);
}
__device__ __forceinline__ uint32_t aload(const uint32_t* p) {
  return __hip_atomic_load(p, __ATOMIC_RELAXED, __HIP_MEMORY_SCOPE_AGENT);
}
__device__ __forceinline__ void astore(uint32_t* p, uint32_t v) {
  __hip_atomic_store(p, v, __ATOMIC_RELAXED, __HIP_MEMORY_SCOPE_AGENT);
}

// validate prefetched VP (retry-reload until every word carries `tag`),
// then unpack to the slot's A-frag LDS buffer (r9-verified math/layout).
#define VALIDATE_UNPACK(VP)                                                    \
  {                                                                            \
    for (;;) {                                                                 \
      uint32_t bad = 0;                                                        \
      _Pragma("unroll")                                                        \
      for (int i = 0; i < 32; ++i) bad |= VP[i] ^ tag;                         \
      if (__any((int)(bad & 0x7FFu)) == 0) break;                              \
      _Pragma("unroll")                                                        \
      for (int i = 0; i < 32; ++i) VP[i] = aload(src + 256 * i);               \
    }                                                                          \
    _Pragma("unroll")                                                          \
    for (int i = 0; i < 32; ++i) {                                             \
      float hh = (float)(((int)VP[i]) >> 11) * rcp20;                          \
      uint32_t uh = __builtin_bit_cast(uint32_t, hh) & 0xFFFF0000u;            \
      float ll = hh - __builtin_bit_cast(float, uh);                           \
      uint32_t pk = __builtin_amdgcn_perm(__builtin_bit_cast(uint32_t, ll),    \
                                          uh, 0x07060302u);                    \
      uint32_t pp = (uint32_t)__shfl_xor((int)pk, 1);                          \
      dbase[128 * i + dword0] = __builtin_amdgcn_perm(pp, pk, psel);           \
    }                                                                          \
  }

#define ISSUE_PREFETCH(VP)                                                     \
  {                                                                            \
    _Pragma("unroll")                                                          \
    for (int i = 0; i < 32; ++i) VP[i] = aload(psrc + 256 * i);                \
  }

__global__ __launch_bounds__(256, 1) void charrnn_kernel(
    const int* __restrict__ xin,
    const float* __restrict__ emb,
    const float* __restrict__ wih,
    const float* __restrict__ whh,
    const float* __restrict__ bih,
    const float* __restrict__ bhh,
    const float* __restrict__ wfc,
    const float* __restrict__ bfc,
    float* __restrict__ out,
    uint32_t* __restrict__ hx)
{
  // A-frag LDS double buffer (by slot parity): idx16 = ks*512 + lane*8 + j
  __shared__ __align__(16) unsigned short a_hi[2][16 * 512];  // 32 KB
  __shared__ __align__(16) unsigned short a_lo[2][16 * 512];  // 32 KB
  __shared__ float ep[VOCAB * PJC];                           // 16.9 KB
  __shared__ unsigned char xtok[GPC * 16 * 1024];             // 64 KB
  __shared__ __align__(16) float red[2][256];                 // 2 KB
  // total ~147 KB

  const int tid  = threadIdx.x;
  const int wave = tid >> 6;
  const int lane = tid & 63;
  const int col  = lane & 15;
  const int quad = lane >> 4;
  const int cl   = blockIdx.x & 1;
  const int m    = blockIdx.x >> 1;

  // ---- weight fragments -> registers (r5-verified) ----
  bf16x8 wfh[16], wfl[16], wfcf[8];
  if (wave < 2) {
    const int nrow = m * 32 + wave * 16 + col;
    const float* wr = whh + (size_t)nrow * HID + quad * 8;
    #pragma unroll
    for (int ks = 0; ks < 16; ++ks) {
      bf16x8 hi, lo;
      #pragma unroll
      for (int j = 0; j < 8; ++j) {
        float w = wr[ks * 32 + j];
        unsigned short h = f2bf(w);
        hi[j] = (short)h;
        lo[j] = (short)f2bf(w - bf2f(h));
      }
      wfh[ks] = hi; wfl[ks] = lo;
    }
  } else {
    const int vrow = m * 8 + (col & 7);
    const float* wr = wfc + (size_t)vrow * HID + (wave - 2) * 256 + quad * 8;
    #pragma unroll
    for (int ks = 0; ks < 8; ++ks) {
      bf16x8 f;
      #pragma unroll
      for (int j = 0; j < 8; ++j) f[j] = (short)f2bf(wr[ks * 32 + j]);
      wfcf[ks] = f;
    }
  }
  const float bfcr = bfc[m * 8 + (col & 7)];

  // ---- LDS init: zero BOTH A-buffers (t=0 reads zeros), ep, tokens ----
  for (int i = tid; i < 2 * 16 * 512; i += 256) {
    ((unsigned short*)a_hi)[i] = 0; ((unsigned short*)a_lo)[i] = 0;
  }
  for (int i = tid; i < VOCAB * 32; i += 256) {
    int v = i >> 5, jl = i & 31;
    int jg = m * 32 + jl;
    float s = bih[jg] + bhh[jg];
    #pragma unroll
    for (int e = 0; e < EMB; ++e) s += emb[v * EMB + e] * wih[jg * EMB + e];
    ep[v * PJC + jl] = s;
  }
  for (int i = tid; i < GPC * 16 * 1024; i += 256) {
    int g = i >> 14, b = (i >> 10) & 15, t = i & 1023;
    xtok[i] = (unsigned char)xin[((cl * GPC + g) * 16 + b) * TT + t];
  }
  __syncthreads();

  // ---- per-lane constants (r9-verified frag-linear mapping) ----
  const int jl = wave * 16 + col;                         // rec waves
  const int C0 = m * 512 + ((wave * 2 + (col >> 3)) << 7) + (col & 7);
  const float rcp20 = 1.f / 1048576.f;
  const uint32_t psel = (tid & 1) ? 0x03020706u : 0x05040100u;
  const int dword0 = tid >> 1;

  uint32_t vpA[32], vpB[32];   // prefetch banks (slot parity), static idx
  #pragma unroll
  for (int i = 0; i < 32; ++i) { vpA[i] = 0; vpB[i] = 0; }
  f32x4 prev_lacc = {0.f, 0.f, 0.f, 0.f};

  // ---- slot loop: slot s -> (group g = s&3, gen t = s>>2) ----
  #pragma unroll 1
  for (int s = 0; s < NSLOT; ++s) {
    const int g  = s & 3,       t  = s >> 2;
    const int g1 = (s - 1) & 3, t1 = (s - 1) >> 2;   // prev slot decode
    const bool valid = s < NVALID;
    const bool ndata = valid && t >= 1;
    const bool dorec = valid && t < TT;
    const int  sb    = s & 1;

    // -- phase A: logits partials (computed at slot s-1) to red --
    if (wave >= 2 && s >= 1 && t1 >= 1) {
      *(f32x4*)&red[wave - 2][lane * 4] = prev_lacc;
    }

    // -- phase B: validate prefetched gen-t data, unpack to buf[sb] --
    if (ndata) {
      const uint32_t tag = (uint32_t)t & 0x7FFu;
      const uint32_t* src = hx + ((cl * GPC + g) * 2 + (t & 1)) * CLW + tid;
      uint32_t* const dbase = (tid & 1) ? (uint32_t*)a_lo[sb]
                                        : (uint32_t*)a_hi[sb];
      if (s & 1) VALIDATE_UNPACK(vpB)
      else       VALIDATE_UNPACK(vpA)
    }
    __syncthreads();  // B1: buf[sb] ready; red stored

    // -- phase C --
    // (0) prefetch for slot s+2 (same parity bank, just consumed).
    //     Data was published at slot s-2 => ~2-slot visibility margin.
    {
      const int sp = s + 2, gp = sp & 3, tp = sp >> 2;
      if (sp < NVALID && tp >= 1) {
        const uint32_t* psrc =
            hx + ((cl * GPC + gp) * 2 + (tp & 1)) * CLW + tid;
        if (s & 1) ISSUE_PREFETCH(vpB)
        else       ISSUE_PREFETCH(vpA)
      }
    }
    if (wave < 2) {
      // recurrence for (g, t) -> publish gen t+1 (tagged, fire-and-forget)
      if (dorec) {
        f32x4 acc0 = {0.f,0.f,0.f,0.f}, acc1 = {0.f,0.f,0.f,0.f}, acc2 = {0.f,0.f,0.f,0.f};
        #pragma unroll
        for (int ks = 0; ks < 16; ++ks) {
          bf16x8 ah = *(const bf16x8*)&a_hi[sb][ks * 512 + lane * 8];
          bf16x8 al = *(const bf16x8*)&a_lo[sb][ks * 512 + lane * 8];
          acc0 = MFMA16(ah, wfh[ks], acc0, 0, 0, 0);
          acc1 = MFMA16(al, wfh[ks], acc1, 0, 0, 0);
          acc2 = MFMA16(ah, wfl[ks], acc2, 0, 0, 0);
        }
        const uint32_t ntag = (uint32_t)(t + 1) & 0x7FFu;
        uint32_t* wb = hx + ((cl * GPC + g) * 2 + ((t + 1) & 1)) * CLW + C0;
        #pragma unroll
        for (int i = 0; i < 4; ++i) {
          const int b = quad * 4 + i;
          float z = acc0[i] + acc1[i] + acc2[i]
                  + ep[(int)xtok[g * 16384 + b * 1024 + t] * PJC + jl];
          float h = ftanh(z);
          int q = __float2int_rn(h * 1048576.f);
          q = max(min(q, 1048575), -1048576);
          astore(wb + b * 8, ((uint32_t)q << 11) | ntag);
        }
        // fire-and-forget: no ack, no flag — tags carry correctness.
      }
    } else {
      // out-store for (g1, t1-1) from red (slot s-1's logits partials)
      if (wave == 2 && s >= 1 && t1 >= 1 && col < 8) {
        #pragma unroll
        for (int i = 0; i < 4; ++i) {
          const int b = quad * 4 + i;
          float v = red[0][lane * 4 + i] + red[1][lane * 4 + i] + bfcr;
          out[((size_t)((cl * GPC + g1) * 16 + b) * TT + (t1 - 1)) * VOCAB
              + m * 8 + col] = v;
        }
      }
      // logits MFMA for (g, gen t) = logits time t-1 (k-half per wave)
      if (valid && t >= 1) {
        f32x4 lacc = {0.f, 0.f, 0.f, 0.f};
        const int kb = (wave - 2) * 8;
        #pragma unroll
        for (int ks = 0; ks < 8; ++ks) {
          bf16x8 ah = *(const bf16x8*)&a_hi[sb][(kb + ks) * 512 + lane * 8];
          bf16x8 al = *(const bf16x8*)&a_lo[sb][(kb + ks) * 512 + lane * 8];
          lacc = MFMA16(ah, wfcf[ks], lacc, 0, 0, 0);
          lacc = MFMA16(al, wfcf[ks], lacc, 0, 0, 0);
        }
        prev_lacc = lacc;
      }
    }
    __syncthreads();  // B2: buf consumed; red consumed
  }
}

extern "C" void kernel_launch(void* const* d_in, const int* in_sizes, int n_in,
                              void* d_out, int out_size, void* d_ws, size_t ws_size,
                              hipStream_t stream) {
  (void)in_sizes; (void)n_in; (void)out_size;
  const size_t dbytes = (size_t)NCLUST * GPC * 2 * CLW * sizeof(uint32_t); // 512 KB
  if (ws_size < dbytes) return;

  const int*   x    = (const int*)d_in[0];
  const float* embp = (const float*)d_in[1];
  const float* W_ih = (const float*)d_in[2];
  const float* W_hh = (const float*)d_in[3];
  const float* b_ih = (const float*)d_in[4];
  const float* b_hh = (const float*)d_in[5];
  const float* W_fc = (const float*)d_in[6];
  const float* b_fc = (const float*)d_in[7];

  // zero the whole data region: residual tags from a previous replay could
  // alias live gens (tag space 2048 < 2 runs); tag 0 matches no live gen.
  hipMemsetAsync(d_ws, 0, dbytes, stream);

  charrnn_kernel<<<NWG, 256, 0, stream>>>(x, embp, W_ih, W_hh, b_ih, b_hh,
                                          W_fc, b_fc, (float*)d_out,
                                          (uint32_t*)d_ws);
}

// Round 8
// 8972.021 us; speedup vs baseline: 2.9280x; 1.6996x over previous
//
#include <hip/hip_runtime.h>
#include <cstdint>

// CharRNN fused kernel, round 12 — MI355X (gfx950).
//
// Measured history driving this design:
//  r5 (3018us): agent exchange legs ~900cy, serialized ~7k cy/step.
//  r7/r8: XCD-local load shortcuts UNSOUND (stale L1/L2). Agent loads only.
//  r9 (3459us): per-word tags work but zero-margin speculation misses.
//  r10 (26ms): W_hh can never be single-CU-resident (VGPR file = 2048/CU).
//  r11 (15.2ms): slot-pipelined groups defeated by __syncthreads' implicit
//    s_waitcnt vmcnt(0) drain — prefetches force-completed per slot
//    (8930cy/slot); FETCH 528MB = 4x r5 => margins fine, drain = whole story.
//
// Round-12 = r11 schedule + two fixes:
//  (1) RAW barriers (lgkmcnt(0); s_barrier; memory-fenced) — loads stay in
//      flight across slots; ONE barrier/slot (A-bufs + red parity-buffered).
//  (2) r5 pre-packed hi/lo payload (NO reader unpack; B = 32x ds_write_b32)
//      + DEFERRED TAG-WORD release: writer stores 4 data words at C(s);
//      at C(s+1) a counted s_waitcnt vmcnt(33 ok / 1 slow) retires exactly
//      [old tagword + 4 old data stores] while this slot's 32 data loads +
//      1 tag load stay in flight; then stores tagword=gen. Reader pipeline:
//      tagline load 2 slots ahead; check + issue 32 data loads 1 slot ahead
//      — loads issued only AFTER observing the tag => acquire-sound (tag
//      committed after ack'd data => later-issued loads see the data).
//      Tag miss -> per-wave r5 poll+sweep fallback (rare; deadlock-free:
//      writers never wait on readers; barrier is WG-local).
// Overwrite safety (distance-2, via tagword chain): any member's (g,t+2)
// stores follow ALL members' tagword(t+1), which follow each member's own
// B-consume of (g,t). Data region needs no init (gated by fresh flags).

typedef short bf16x8 __attribute__((ext_vector_type(8)));
typedef float f32x4 __attribute__((ext_vector_type(4)));

#define VOCAB 128
#define EMB   16
#define HID   512
#define TT    1024
#define GPC   4
#define NCLUST 2
#define MEMB  16
#define NWG   (NCLUST * MEMB)
#define CLW   8192                       // dwords per (cl,g,par): 32 KB
#define FLAGOFF (NCLUST * GPC * 2 * CLW) // 131072
#define PJC   33
#define NVALID (GPC * (TT + 1))          // 4100
#define NSLOT  (NVALID + 1)

#define MFMA16 __builtin_amdgcn_mfma_f32_16x16x32_bf16
#define BARRIER() do {                                      \
    asm volatile("s_waitcnt lgkmcnt(0)" ::: "memory");      \
    __builtin_amdgcn_s_barrier();                           \
    asm volatile("" ::: "memory"); } while (0)

__device__ __forceinline__ unsigned short f2bf(float f) {
  uint32_t u = __builtin_bit_cast(uint32_t, f);
  u += 0x7FFFu + ((u >> 16) & 1u);
  return (unsigned short)(u >> 16);
}
__device__ __forceinline__ float bf2f(unsigned short s) {
  uint32_t u = (uint32_t)s << 16;
  return __builtin_bit_cast(float, u);
}
__device__ __forceinline__ float ftanh(float z) {
  z = fminf(15.f, fmaxf(-15.f, z));
  float e = __expf(2.f * z);
  return (e - 1.f) * __builtin_amdgcn_rcpf(e + 1.f);
}
__device__ __forceinline__ uint32_t aload(const uint32_t* p) {
  return __hip_atomic_load(p, __ATOMIC_RELAXED, __HIP_MEMORY_SCOPE_AGENT);
}
__device__ __forceinline__ void astore(uint32_t* p, uint32_t v) {
  __hip_atomic_store(p, v, __ATOMIC_RELAXED, __HIP_MEMORY_SCOPE_AGENT);
}

__global__ __launch_bounds__(256, 1) void charrnn_kernel(
    const int* __restrict__ xin,
    const float* __restrict__ emb,
    const float* __restrict__ wih,
    const float* __restrict__ whh,
    const float* __restrict__ bih,
    const float* __restrict__ bhh,
    const float* __restrict__ wfc,
    const float* __restrict__ bfc,
    float* __restrict__ out,
    uint32_t* __restrict__ hx)
{
  __shared__ __align__(16) unsigned short a_hi[2][16 * 512];  // 32 KB
  __shared__ __align__(16) unsigned short a_lo[2][16 * 512];  // 32 KB
  __shared__ float ep[VOCAB * PJC];                           // 16.9 KB
  __shared__ unsigned char xtok[GPC * 16 * 1024];             // 64 KB
  __shared__ __align__(16) float red[2][256];                 // 2 KB

  const int tid  = threadIdx.x;
  const int wave = tid >> 6;
  const int lane = tid & 63;
  const int col  = lane & 15;
  const int quad = lane >> 4;
  const int cl   = blockIdx.x & 1;
  const int m    = blockIdx.x >> 1;

  // ---- weight fragments -> registers (r5-verified) ----
  bf16x8 wfh[16], wfl[16], wfcf[8];
  if (wave < 2) {
    const int nrow = m * 32 + wave * 16 + col;
    const float* wr = whh + (size_t)nrow * HID + quad * 8;
    #pragma unroll
    for (int ks = 0; ks < 16; ++ks) {
      bf16x8 hi, lo;
      #pragma unroll
      for (int j = 0; j < 8; ++j) {
        float w = wr[ks * 32 + j];
        unsigned short h = f2bf(w);
        hi[j] = (short)h;
        lo[j] = (short)f2bf(w - bf2f(h));
      }
      wfh[ks] = hi; wfl[ks] = lo;
    }
  } else {
    const int vrow = m * 8 + (col & 7);
    const float* wr = wfc + (size_t)vrow * HID + (wave - 2) * 256 + quad * 8;
    #pragma unroll
    for (int ks = 0; ks < 8; ++ks) {
      bf16x8 f;
      #pragma unroll
      for (int j = 0; j < 8; ++j) f[j] = (short)f2bf(wr[ks * 32 + j]);
      wfcf[ks] = f;
    }
  }
  const float bfcr = bfc[m * 8 + (col & 7)];

  // ---- LDS init: zero BOTH A-buffers (t=0 reads zeros), ep, tokens ----
  for (int i = tid; i < 2 * 16 * 512; i += 256) {
    ((unsigned short*)a_hi)[i] = 0; ((unsigned short*)a_lo)[i] = 0;
  }
  for (int i = tid; i < VOCAB * 32; i += 256) {
    int v = i >> 5, jl0 = i & 31;
    int jg = m * 32 + jl0;
    float s = bih[jg] + bhh[jg];
    #pragma unroll
    for (int e = 0; e < EMB; ++e) s += emb[v * EMB + e] * wih[jg * EMB + e];
    ep[v * PJC + jl0] = s;
  }
  for (int i = tid; i < GPC * 16 * 1024; i += 256) {
    int g = i >> 14, b = (i >> 10) & 15, t = i & 1023;
    xtok[i] = (unsigned char)xin[((cl * GPC + g) * 16 + b) * TT + t];
  }
  __syncthreads();   // one-time; drain harmless

  // ---- per-lane constants ----
  const int jl = wave * 16 + col;                 // rec-wave hid col
  uint32_t* const flagbase = hx + FLAGOFF;        // (cl*4+g)*32 lines

  uint32_t v[32];                                 // data-load bank
  uint32_t ftag = 0;
  bool okc = false;                               // loads issued for s+1?
  bool prev_live = false;                         // rec: ack+tagword pending
  uint32_t prev_val = 0;
  uint32_t* prev_fp = flagbase;
  f32x4 prev_lacc = {0.f, 0.f, 0.f, 0.f};        // wave2 logits partial

  #pragma unroll 1
  for (int s = 0; s < NSLOT; ++s) {
    const int g = s & 3, t = s >> 2;
    const int sb = s & 1;
    const bool valid = s < NVALID;
    const bool ndata = valid && t >= 1;
    const bool dorec = valid && t < TT && wave < 2;
    const bool dolog = valid && t >= 1 && wave >= 2;

    // ---- phase B: consume (g,t) -> buf[sb] (pure copy, no unpack) ----
    if (ndata) {
      if (!okc) {   // slow path (per-wave): poll tagwords, then sweep
        const uint32_t* fl = flagbase + ((cl << 2) + g) * 32 + (lane & 31);
        uint32_t f;
        do { f = aload(fl); } while (__all((int)(f >= (uint32_t)t)) == 0);
        const uint32_t* src =
            hx + (((cl << 2) + g) * 2 + (t & 1)) * CLW + tid;
        #pragma unroll
        for (int i = 0; i < 32; ++i) v[i] = aload(src + 256 * i);
      }
      uint32_t* bh = (uint32_t*)a_hi[sb];
      uint32_t* bl = (uint32_t*)a_lo[sb];
      #pragma unroll
      for (int i = 0; i < 16; ++i) bh[tid + 256 * i] = v[i];
      #pragma unroll
      for (int i = 0; i < 16; ++i) bl[tid + 256 * i] = v[16 + i];
    }
    BARRIER();   // buf[sb] ready; red(parity) ready; loads/stores unhindered

    // ---- phase C ----
    // (1) tag check for s+1; issue its 32 data loads if tags show arrival
    {
      const int s1 = s + 1, g1 = s1 & 3, t1n = s1 >> 2;
      okc = false;
      if (s1 < NVALID && t1n >= 1) {
        okc = __all((int)(ftag >= (uint32_t)t1n)) != 0;
        if (okc) {
          const uint32_t* src =
              hx + (((cl << 2) + g1) * 2 + (t1n & 1)) * CLW + tid;
          #pragma unroll
          for (int i = 0; i < 32; ++i) v[i] = aload(src + 256 * i);
        }
      }
    }
    // (2) tagline prefetch for s+2 (always issue; dummy line if off-range)
    {
      const int s2 = s + 2, g2 = s2 & 3, t2 = s2 >> 2;
      const uint32_t* tl = (s2 < NVALID && t2 >= 1)
          ? (flagbase + ((cl << 2) + g2) * 32) : flagbase;
      ftag = aload(tl + (lane & 31));
    }
    // (3) deferred release for slot s-1's publish: counted ack + tagword.
    //     Queue (old->new): [tagword(s-1), 4 stores(s-1) | 32 loads, 1 tag]
    //     vmcnt(33) retires exactly the old 5; vmcnt(1) when loads skipped.
    if (wave < 2 && prev_live) {
      if (okc) asm volatile("s_waitcnt vmcnt(33)" ::: "memory");
      else     asm volatile("s_waitcnt vmcnt(1)"  ::: "memory");
      if (lane == 0) astore(prev_fp, prev_val);
    }
    // (4) compute
    if (dorec) {
      f32x4 acc0 = {0.f,0.f,0.f,0.f}, acc1 = {0.f,0.f,0.f,0.f}, acc2 = {0.f,0.f,0.f,0.f};
      #pragma unroll
      for (int ks = 0; ks < 16; ++ks) {
        bf16x8 ah = *(const bf16x8*)&a_hi[sb][ks * 512 + lane * 8];
        bf16x8 al = *(const bf16x8*)&a_lo[sb][ks * 512 + lane * 8];
        acc0 = MFMA16(ah, wfh[ks], acc0, 0, 0, 0);
        acc1 = MFMA16(al, wfh[ks], acc1, 0, 0, 0);
        acc2 = MFMA16(ah, wfl[ks], acc2, 0, 0, 0);
      }
      // publish gen t+1: r5 writer (hi/lo split + shfl pair-pack + 4 stores)
      uint32_t* wb = hx + (((cl << 2) + g) * 2 + ((t + 1) & 1)) * CLW
                   + ((lane & 1) ? 4096 : 0)
                   + m * 256 + (wave * 2 + (col >> 3)) * 64 + ((col & 7) >> 1);
      #pragma unroll
      for (int i = 0; i < 4; ++i) {
        const int b = quad * 4 + i;
        float z = acc0[i] + acc1[i] + acc2[i]
                + ep[(int)xtok[g * 16384 + b * 1024 + t] * PJC + jl];
        float h = ftanh(z);
        unsigned short hi = f2bf(h);
        unsigned short lo = f2bf(h - bf2f(hi));
        uint32_t pk = (uint32_t)hi | ((uint32_t)lo << 16);
        uint32_t pp = (uint32_t)__shfl_xor((int)pk, 1);
        uint32_t word = (lane & 1) ? ((pp >> 16) | (pk & 0xFFFF0000u))
                                   : ((pk & 0xFFFFu) | (pp << 16));
        astore(wb + b * 4, word);
      }
      prev_live = true;
      prev_val  = (uint32_t)(t + 1);
      prev_fp   = flagbase + ((cl << 2) + g) * 32 + m * 2 + wave;
    } else if (wave < 2) {
      prev_live = false;
    }
    if (wave >= 2) {
      // out-store for slot s-1 (wave2: own reg partial + wave3's from red)
      if (wave == 2 && s >= 1 && col < 8) {
        const int pg = (s - 1) & 3, pt = (s - 1) >> 2;
        if (pt >= 1 && (s - 1) < NVALID) {
          #pragma unroll
          for (int i = 0; i < 4; ++i) {
            const int b = quad * 4 + i;
            float vv = prev_lacc[i] + red[(s - 1) & 1][lane * 4 + i] + bfcr;
            out[((size_t)((cl * GPC + pg) * 16 + b) * TT + (pt - 1)) * VOCAB
                + m * 8 + col] = vv;
          }
        }
      }
      // logits partial for (g, gen t): k-half per wave
      if (dolog) {
        f32x4 lacc = {0.f, 0.f, 0.f, 0.f};
        const int kb = (wave - 2) * 8;
        #pragma unroll
        for (int ks = 0; ks < 8; ++ks) {
          bf16x8 ah = *(const bf16x8*)&a_hi[sb][(kb + ks) * 512 + lane * 8];
          bf16x8 al = *(const bf16x8*)&a_lo[sb][(kb + ks) * 512 + lane * 8];
          lacc = MFMA16(ah, wfcf[ks], lacc, 0, 0, 0);
          lacc = MFMA16(al, wfcf[ks], lacc, 0, 0, 0);
        }
        if (wave == 3) *(f32x4*)&red[sb][lane * 4] = lacc;
        else           prev_lacc = lacc;
      }
    }
  }
}

extern "C" void kernel_launch(void* const* d_in, const int* in_sizes, int n_in,
                              void* d_out, int out_size, void* d_ws, size_t ws_size,
                              hipStream_t stream) {
  (void)in_sizes; (void)n_in; (void)out_size;
  const size_t need = (size_t)(FLAGOFF + NCLUST * GPC * 32) * sizeof(uint32_t);
  if (ws_size < need) return;   // 512 KB data + 1 KB flags

  const int*   x    = (const int*)d_in[0];
  const float* embp = (const float*)d_in[1];
  const float* W_ih = (const float*)d_in[2];
  const float* W_hh = (const float*)d_in[3];
  const float* b_ih = (const float*)d_in[4];
  const float* b_hh = (const float*)d_in[5];
  const float* W_fc = (const float*)d_in[6];
  const float* b_fc = (const float*)d_in[7];

  // zero ONLY the tagword region: data is gated by fresh tagwords + acks.
  hipMemsetAsync((uint32_t*)d_ws + FLAGOFF, 0,
                 NCLUST * GPC * 32 * sizeof(uint32_t), stream);

  charrnn_kernel<<<NWG, 256, 0, stream>>>(x, embp, W_ih, W_hh, b_ih, b_hh,
                                          W_fc, b_fc, (float*)d_out,
                                          (uint32_t*)d_ws);
}